// Round 3
// baseline (584.375 us; speedup 1.0000x reference)
//
#include <hip/hip_runtime.h>
#include <hip/hip_bf16.h>
#include <stdint.h>

typedef __attribute__((ext_vector_type(8))) short s8v;
typedef __attribute__((ext_vector_type(4))) float f32x4;

__device__ __forceinline__ unsigned short f2bf(float f) {
  unsigned u = __builtin_bit_cast(unsigned, f);
  u += 0x7fffu + ((u >> 16) & 1u);
  return (unsigned short)(u >> 16);
}

__device__ __forceinline__ void gl16(const void* g, void* l) {
  __builtin_amdgcn_global_load_lds(
      (const __attribute__((address_space(1))) unsigned int*)g,
      (__attribute__((address_space(3))) unsigned int*)l,
      16, 0, 0);
}

// ---------------- prep kernels ----------------

__global__ void cast_bf16_k(const float* __restrict__ s, unsigned short* __restrict__ d, int n4) {
  int i = blockIdx.x * blockDim.x + threadIdx.x;
  if (i < n4) {
    float4 v = reinterpret_cast<const float4*>(s)[i];
    ushort4 o;
    o.x = f2bf(v.x); o.y = f2bf(v.y); o.z = f2bf(v.z); o.w = f2bf(v.w);
    reinterpret_cast<ushort4*>(d)[i] = o;
  }
}

__global__ void prep_conv(
    const float* w0, const float* w1, const float* w2, const float* w3,
    const float* w4, const float* w5, const float* w6,
    const float* b0, const float* b1, const float* b2, const float* b3,
    const float* b4, const float* b5, const float* b6,
    unsigned short* __restrict__ Mt, float* __restrict__ cbias)
{
  int n = blockIdx.x * blockDim.x + threadIdx.x;
  if (n >= 3712) return;
  unsigned short* row = Mt + n * 256;
  for (int i = 0; i < 256; ++i) row[i] = 0;
  if (n >= 3648) { cbias[n] = 0.f; return; }
  const int khs[7] = {1,2,1,3,1,4,2};
  const int kws[7] = {2,1,3,1,4,1,2};
  const int cs[8]  = {0,768,1536,2048,2560,2816,3072,3648};
  const float* ws[7] = {w0,w1,w2,w3,w4,w5,w6};
  const float* bs[7] = {b0,b1,b2,b3,b4,b5,b6};
  int k = 6;
  while (n < cs[k]) --k;
  const int kh = khs[k], kw = kws[k];
  const int ow = 5 - kw, np = (5 - kh) * ow;
  const int r = n - cs[k];
  const int och = r / np, p = r % np;
  const int oi = p / ow, oj = p % ow;
  const float* w = ws[k];
  cbias[n] = bs[k][och];
  for (int c = 0; c < 16; ++c)
    for (int dh = 0; dh < kh; ++dh)
      for (int dw = 0; dw < kw; ++dw)
        row[c * 16 + (oi + dh) * 4 + (oj + dw)] =
            f2bf(w[((och * 16 + c) * kh + dh) * kw + dw]);
}

__global__ void prep_fw0(const float* __restrict__ fw0, unsigned short* __restrict__ outp) {
  int idx = blockIdx.x * 256 + threadIdx.x;  // 512*3712
  int nrow = idx / 3712;
  int k = idx - nrow * 3712;
  outp[idx] = (k < 3648) ? f2bf(fw0[nrow * 3648 + k]) : (unsigned short)0;
}

// ---------------- fused conv + FC1 ----------------
// Per block: 128 rows of x. h1[128][512] = relu( relu(x·Mt^T+cb) · fw0^T + fb0 ).
// 8 waves (2M x 4N). LDS 128KB: xs 64K (persistent), ms 32K (Mt k-half), ps 32K (P).
// All LDS tiles XOR-swizzled (slot16 ^= row&7); gl16 dest linear, global src pre-swizzled.
__global__ __launch_bounds__(512, 2) void fused_conv_fc1(
    const unsigned short* __restrict__ xb,   // [32768][256]
    const unsigned short* __restrict__ Mt,   // [3712][256]
    const float* __restrict__ cbias,         // [3712]
    const unsigned short* __restrict__ fw0b, // [512][3712]
    const float* __restrict__ fb0,           // [512]
    unsigned short* __restrict__ h1)         // [32768][512]
{
  __shared__ unsigned short xs[128 * 256];  // row stride 512B
  __shared__ unsigned short ms[128 * 128];  // row stride 256B
  __shared__ unsigned short ps[128 * 128];  // row stride 256B
  const int tid = threadIdx.x;
  const int lane = tid & 63;
  const int w = tid >> 6;
  const int wm = w >> 2;   // 0..1 : 64-row half
  const int wn = w & 3;    // 0..3
  const int g8 = lane >> 4;        // k sub-slice group
  const int l15 = lane & 15;
  const int m0 = blockIdx.x * 128;

  // stage xs once (swizzled content via pre-swizzled global col)
  {
    char* dst = (char*)xs + (w * 8) * 1024 + lane * 16;
#pragma unroll
    for (int i = 0; i < 8; ++i) {
      int c = (w * 8 + i) * 64 + lane;       // 0..4095
      int row = c >> 5, col16 = c & 31;
      int cs = col16 ^ (row & 7);
      gl16(xb + (size_t)(m0 + row) * 256 + cs * 8, dst + i * 1024);
    }
  }

  f32x4 acc[4][8] = {};

#pragma unroll 1
  for (int j = 0; j < 29; ++j) {
    f32x4 accp[4][2] = {};
    const int ar = wm * 64 + l15;   // x row for conv A-frags
    const int br = wn * 32 + l15;   // conv-output row base for B-frags
#pragma unroll 1
    for (int h = 0; h < 2; ++h) {
      __syncthreads();  // prior readers of ms/ps done
      {
        char* dst = (char*)ms + (w * 4) * 1024 + lane * 16;
#pragma unroll
        for (int i = 0; i < 4; ++i) {
          int c = (w * 4 + i) * 64 + lane;   // 0..2047
          int row = c >> 4, col16 = c & 15;
          int cs = col16 ^ (row & 7);
          gl16(Mt + (size_t)(j * 128 + row) * 256 + h * 128 + cs * 8, dst + i * 1024);
        }
      }
      __syncthreads();  // ms(h) ready (vmcnt drained)
#pragma unroll
      for (int kk = 0; kk < 4; ++kk) {
        const int cx = h * 16 + kk * 4 + g8;   // xs col16
        const int cm = kk * 4 + g8;            // ms col16
        s8v xa[4], mb[2];
#pragma unroll
        for (int mi = 0; mi < 4; ++mi) {
          int r = ar + mi * 16;
          xa[mi] = *(const s8v*)((const char*)xs + r * 512 + ((cx ^ (r & 7)) << 4));
        }
#pragma unroll
        for (int ni = 0; ni < 2; ++ni) {
          int r = br + ni * 16;
          mb[ni] = *(const s8v*)((const char*)ms + r * 256 + ((cm ^ (r & 7)) << 4));
        }
#pragma unroll
        for (int mi = 0; mi < 4; ++mi)
#pragma unroll
          for (int ni = 0; ni < 2; ++ni)
            accp[mi][ni] = __builtin_amdgcn_mfma_f32_16x16x32_bf16(
                xa[mi], mb[ni], accp[mi][ni], 0, 0, 0);
      }
    }
    // write P = relu(conv + bias) as bf16, swizzled
#pragma unroll
    for (int ni = 0; ni < 2; ++ni) {
      const int pc = wn * 32 + ni * 16 + l15;
      const float bv = cbias[j * 128 + pc];
#pragma unroll
      for (int mi = 0; mi < 4; ++mi) {
#pragma unroll
        for (int r = 0; r < 4; ++r) {
          const int pr = wm * 64 + mi * 16 + g8 * 4 + r;
          float v = accp[mi][ni][r] + bv;
          v = v > 0.f ? v : 0.f;
          *(unsigned short*)((char*)ps + pr * 256 +
                             (((pc >> 3) ^ (pr & 7)) << 4) + (pc & 7) * 2) = f2bf(v);
        }
      }
    }
    __syncthreads();  // P complete

    // FC1 partial: acc += P · fw0_j^T   (B-frags straight from global/L2)
    const int kbase = j * 128;
#pragma unroll
    for (int kk = 0; kk < 4; ++kk) {
      const int c16 = kk * 4 + g8;   // 0..15
      s8v pa[4], fwb[8];
#pragma unroll
      for (int mi = 0; mi < 4; ++mi) {
        int r = wm * 64 + mi * 16 + l15;
        pa[mi] = *(const s8v*)((const char*)ps + r * 256 + ((c16 ^ (r & 7)) << 4));
      }
      const int kf = kbase + kk * 32 + g8 * 8;
#pragma unroll
      for (int ni = 0; ni < 8; ++ni) {
        int bn = wn * 128 + ni * 16 + l15;
        fwb[ni] = *(const s8v*)(fw0b + (size_t)bn * 3712 + kf);
      }
#pragma unroll
      for (int mi = 0; mi < 4; ++mi)
#pragma unroll
        for (int ni = 0; ni < 8; ++ni)
          acc[mi][ni] = __builtin_amdgcn_mfma_f32_16x16x32_bf16(
              pa[mi], fwb[ni], acc[mi][ni], 0, 0, 0);
    }
  }

  // epilogue: h1 = relu(acc + fb0) -> bf16
#pragma unroll
  for (int ni = 0; ni < 8; ++ni) {
    const int col = wn * 128 + ni * 16 + l15;
    const float bv = fb0[col];
#pragma unroll
    for (int mi = 0; mi < 4; ++mi) {
      const int row = m0 + wm * 64 + mi * 16 + g8 * 4;
#pragma unroll
      for (int r = 0; r < 4; ++r) {
        float v = acc[mi][ni][r] + bv;
        v = v > 0.f ? v : 0.f;
        h1[(size_t)(row + r) * 512 + col] = f2bf(v);
      }
    }
  }
}

// ---------------- FC2 (MFMA) + FC3 (fp32 VALU) fused ----------------
__global__ __launch_bounds__(256) void fc23(
    const unsigned short* __restrict__ h1,
    const unsigned short* __restrict__ fw1b,
    const float* __restrict__ fb1,
    const float* __restrict__ fw2,
    const float* __restrict__ fb2,
    float* __restrict__ out)
{
  __shared__ unsigned short As[64 * 64];
  __shared__ unsigned short Bs[128 * 64];
  __shared__ float h2[64][129];
  const int tid = threadIdx.x;
  const int lane = tid & 63;
  const int wave = tid >> 6;
  const int wm = wave >> 1, wn = wave & 1;
  const int m0 = blockIdx.x * 64;

  f32x4 acc[2][4] = {};

  const unsigned short* Ag = h1 + (size_t)(m0 + (lane >> 3)) * 512 + (lane & 7) * 8;
  const unsigned short* Bg = fw1b + (size_t)(lane >> 3) * 512 + (lane & 7) * 8;
  char* Asb = (char*)As + wave * 2048 + lane * 16;
  char* Bsb = (char*)Bs + wave * 4096 + lane * 16;

  for (int k0 = 0; k0 < 512; k0 += 64) {
#pragma unroll
    for (int i = 0; i < 2; ++i)
      gl16(Ag + (size_t)((wave * 2 + i) * 8) * 512 + k0, Asb + i * 1024);
#pragma unroll
    for (int i = 0; i < 4; ++i)
      gl16(Bg + (size_t)((wave * 4 + i) * 8) * 512 + k0, Bsb + i * 1024);
    __syncthreads();
    const int arow = wm * 32 + (lane & 15);
    const int brow = wn * 64 + (lane & 15);
    const int kc = (lane >> 4) * 8;
    s8v af[2][2], bfv[4][2];
#pragma unroll
    for (int mi = 0; mi < 2; ++mi)
#pragma unroll
      for (int kk = 0; kk < 2; ++kk)
        af[mi][kk] = *(const s8v*)(As + (arow + mi * 16) * 64 + kk * 32 + kc);
#pragma unroll
    for (int ni = 0; ni < 4; ++ni)
#pragma unroll
      for (int kk = 0; kk < 2; ++kk)
        bfv[ni][kk] = *(const s8v*)(Bs + (brow + ni * 16) * 64 + kk * 32 + kc);
#pragma unroll
    for (int kk = 0; kk < 2; ++kk)
#pragma unroll
      for (int mi = 0; mi < 2; ++mi)
#pragma unroll
        for (int ni = 0; ni < 4; ++ni)
          acc[mi][ni] = __builtin_amdgcn_mfma_f32_16x16x32_bf16(
              af[mi][kk], bfv[ni][kk], acc[mi][ni], 0, 0, 0);
    __syncthreads();
  }

#pragma unroll
  for (int ni = 0; ni < 4; ++ni) {
    const int col = wn * 64 + ni * 16 + (lane & 15);
    const float bv = fb1[col];
#pragma unroll
    for (int mi = 0; mi < 2; ++mi) {
      const int rl = wm * 32 + mi * 16 + (lane >> 4) * 4;
#pragma unroll
      for (int r = 0; r < 4; ++r) {
        float v = acc[mi][ni][r] + bv;
        h2[rl + r][col] = v > 0.f ? v : 0.f;
      }
    }
  }
  __syncthreads();

  const int r = tid >> 2, j = tid & 3;
  const float* w = fw2 + j * 128;
  float dot = fb2[j];
#pragma unroll 8
  for (int c = 0; c < 128; ++c) dot += h2[r][c] * w[c];
  out[(size_t)(m0 + r) * 4 + j] = dot;
}

// ---------------- launch ----------------

extern "C" void kernel_launch(void* const* d_in, const int* in_sizes, int n_in,
                              void* d_out, int out_size, void* d_ws, size_t ws_size,
                              hipStream_t stream) {
  const float* x = (const float*)d_in[0];
  const float* w[7];
  const float* b[7];
  for (int i = 0; i < 7; ++i) {
    w[i] = (const float*)d_in[1 + 2 * i];
    b[i] = (const float*)d_in[2 + 2 * i];
  }
  const float* fw0 = (const float*)d_in[15];
  const float* fb0 = (const float*)d_in[16];
  const float* fw1 = (const float*)d_in[17];
  const float* fb1 = (const float*)d_in[18];
  const float* fw2 = (const float*)d_in[19];
  const float* fb2 = (const float*)d_in[20];

  char* ws = (char*)d_ws;
  size_t off = 0;
  auto alloc = [&](size_t bytes) {
    void* p = ws + off;
    off += (bytes + 255) & ~(size_t)255;
    return p;
  };
  unsigned short* Mt   = (unsigned short*)alloc((size_t)3712 * 256 * 2);  // 1.9 MB
  float*          cb   = (float*)alloc((size_t)3712 * 4);
  unsigned short* fw0b = (unsigned short*)alloc((size_t)512 * 3712 * 2);  // 3.8 MB
  unsigned short* fw1b = (unsigned short*)alloc((size_t)128 * 512 * 2);
  unsigned short* xb   = (unsigned short*)alloc((size_t)32768 * 256 * 2); // 16.8 MB
  unsigned short* h1   = (unsigned short*)alloc((size_t)32768 * 512 * 2); // 33.6 MB
  if (ws_size < off) return;  // needs ~56.3 MB

  cast_bf16_k<<<8192, 256, 0, stream>>>(x, xb, 2097152);
  cast_bf16_k<<<64, 256, 0, stream>>>(fw1, fw1b, 16384);
  prep_conv<<<15, 256, 0, stream>>>(w[0], w[1], w[2], w[3], w[4], w[5], w[6],
                                    b[0], b[1], b[2], b[3], b[4], b[5], b[6], Mt, cb);
  prep_fw0<<<7424, 256, 0, stream>>>(fw0, fw0b);

  fused_conv_fc1<<<256, 512, 0, stream>>>(xb, Mt, cb, fw0b, fb0, h1);
  fc23<<<512, 256, 0, stream>>>(h1, fw1b, fb1, fw2, fb2, (float*)d_out);
}